// Round 6
// baseline (263.063 us; speedup 1.0000x reference)
//
#include <hip/hip_runtime.h>
#include <cstdint>
#include <cstddef>

// ---------------------------------------------------------------------------
// Hgru2 (GLA-style gated linear attention), B=4, N=2048, d=1024, h=8, hd=128
//   cast x,W -> bf16
//   gemm_qkv: Q=silu(xWq^T), K=1-sigmoid(xWk^T) (bf16), V (bf16)
//   hgru_scan (C=32, fused): per block (bh, chunk c, v-half):
//       recompute U_{c-1} from K,V of chunk c-1 entirely in LDS (1-term state:
//       per-chunk decay <= e^-10.02 by algebra, truncation ~2e-3);
//       then O = tril(Qh Kt^T) V + Qh U_{c-1}.  No SU buffer, no Qh/Kt
//       writeback: saves ~128 MB of global round-trips vs R5 two-kernel scan.
//   rmsnorm -> bf16;  gemm_out: out = normed @ Wo^T (f32)
// ---------------------------------------------------------------------------

typedef unsigned short u16;
using f32x4  = __attribute__((ext_vector_type(4))) float;
using bf16x8 = __attribute__((ext_vector_type(8))) short;

__device__ __forceinline__ float bf2f(u16 u) {
  union { unsigned int i; float f; } v; v.i = ((unsigned int)u) << 16; return v.f;
}
__device__ __forceinline__ u16 f2bf(float f) {
  union { float f; unsigned int i; } v; v.f = f;
  unsigned int r = v.i + 0x7fffu + ((v.i >> 16) & 1u);
  return (u16)(r >> 16);
}
__device__ __forceinline__ void async_load16(const void* g, void* l) {
  __builtin_amdgcn_global_load_lds(
      (const __attribute__((address_space(1))) unsigned int*)(uintptr_t)g,
      (__attribute__((address_space(3))) unsigned int*)(uintptr_t)l, 16, 0, 0);
}

// ---------------------------------------------------------------------------
// 128x128-tile bf16 GEMM core (R4): single 32KB buffer, 2 barriers/K-step,
// XOR bank swizzle (0 conflicts), loop-invariant addressing.
// ---------------------------------------------------------------------------
__device__ __forceinline__ void gemm128_core(const u16* __restrict__ Ag, const u16* __restrict__ Bg,
                                             u16* smem, f32x4 (&acc)[4][4]) {
  const int tid = threadIdx.x;
  const int lane = tid & 63, wave = tid >> 6;
  const int wm = (wave & 1) * 64, wn = (wave >> 1) * 64;
  const int r = lane & 15, quad = lane >> 4;
  const int xk = r & 7;
  const u16* baseA0 = smem + (wm + r) * 64 + ((quad ^ xk) & 7) * 8;
  const u16* baseA1 = smem + (wm + r) * 64 + (((quad + 4) ^ xk) & 7) * 8;
  const u16* baseB0 = smem + 8192 + (wn + r) * 64 + ((quad ^ xk) & 7) * 8;
  const u16* baseB1 = smem + 8192 + (wn + r) * 64 + (((quad + 4) ^ xk) & 7) * 8;
  const int soff = (tid >> 3) * 1024 + (((tid & 7) ^ ((tid >> 3) & 7)) * 8);
  u16* dA = smem + wave * 512;
  u16* dB = smem + 8192 + wave * 512;
  for (int kt = 0; kt < 16; ++kt) {
    __syncthreads();
    const u16* As = Ag + kt * 64 + soff;
    const u16* Bs = Bg + kt * 64 + soff;
#pragma unroll
    for (int it = 0; it < 4; ++it) {
      async_load16(As + it * 32768, dA + it * 2048);
      async_load16(Bs + it * 32768, dB + it * 2048);
    }
    __syncthreads();
    bf16x8 af[4], bv[4];
#pragma unroll
    for (int i = 0; i < 4; ++i) af[i] = *(const bf16x8*)(baseA0 + i * 1024);
#pragma unroll
    for (int j = 0; j < 4; ++j) bv[j] = *(const bf16x8*)(baseB0 + j * 1024);
#pragma unroll
    for (int i = 0; i < 4; ++i)
#pragma unroll
      for (int j = 0; j < 4; ++j)
        acc[i][j] = __builtin_amdgcn_mfma_f32_16x16x32_bf16(af[i], bv[j], acc[i][j], 0, 0, 0);
#pragma unroll
    for (int i = 0; i < 4; ++i) af[i] = *(const bf16x8*)(baseA1 + i * 1024);
#pragma unroll
    for (int j = 0; j < 4; ++j) bv[j] = *(const bf16x8*)(baseB1 + j * 1024);
#pragma unroll
    for (int i = 0; i < 4; ++i)
#pragma unroll
      for (int j = 0; j < 4; ++j)
        acc[i][j] = __builtin_amdgcn_mfma_f32_16x16x32_bf16(af[i], bv[j], acc[i][j], 0, 0, 0);
  }
}

// ---------------------------------------------------------------------------
__global__ __launch_bounds__(256) void cast_f32_bf16(const float* __restrict__ src,
                                                     u16* __restrict__ dst, int n4) {
  int i = blockIdx.x * 256 + threadIdx.x;
  if (i >= n4) return;
  float4 v = ((const float4*)src)[i];
  unsigned int lo = (unsigned)f2bf(v.x) | ((unsigned)f2bf(v.y) << 16);
  unsigned int hi = (unsigned)f2bf(v.z) | ((unsigned)f2bf(v.w) << 16);
  ((uint2*)dst)[i] = make_uint2(lo, hi);
}

__global__ __launch_bounds__(256) void cast_w4(const float* __restrict__ w0, const float* __restrict__ w1,
                                               const float* __restrict__ w2, const float* __restrict__ w3,
                                               u16* __restrict__ d0, u16* __restrict__ d1,
                                               u16* __restrict__ d2, u16* __restrict__ d3) {
  const float* src = blockIdx.y == 0 ? w0 : (blockIdx.y == 1 ? w1 : (blockIdx.y == 2 ? w2 : w3));
  u16* dst = blockIdx.y == 0 ? d0 : (blockIdx.y == 1 ? d1 : (blockIdx.y == 2 ? d2 : d3));
  int i = blockIdx.x * 256 + threadIdx.x;
  float4 v = ((const float4*)src)[i];
  unsigned int lo = (unsigned)f2bf(v.x) | ((unsigned)f2bf(v.y) << 16);
  unsigned int hi = (unsigned)f2bf(v.z) | ((unsigned)f2bf(v.w) << 16);
  ((uint2*)dst)[i] = make_uint2(lo, hi);
}

// grid (64, 24): y/8 selects {Q,K,V}, y&7 = 128-col block
__global__ __launch_bounds__(256) void hgru_gemm_qkv(
    const u16* __restrict__ Xb, const u16* __restrict__ Wqb, const u16* __restrict__ Wkb,
    const u16* __restrict__ Wvb, u16* __restrict__ Qb, u16* __restrict__ Kb,
    u16* __restrict__ Vb) {
  __shared__ alignas(16) u16 smem[16384];
  const int which = blockIdx.y >> 3, bn = blockIdx.y & 7;
  const u16* W = which == 0 ? Wqb : (which == 1 ? Wkb : Wvb);
  const u16* Ag = Xb + (size_t)blockIdx.x * 128 * 1024;
  const u16* Bg = W + (size_t)bn * 128 * 1024;
  f32x4 acc[4][4] = {};
  gemm128_core(Ag, Bg, smem, acc);
  const int tid = threadIdx.x, lane = tid & 63, wave = tid >> 6;
  const int wm = (wave & 1) * 64, wn = (wave >> 1) * 64;
  const int r = lane & 15, quad = lane >> 4;
#pragma unroll
  for (int i = 0; i < 4; ++i)
#pragma unroll
    for (int j = 0; j < 4; ++j)
#pragma unroll
      for (int reg = 0; reg < 4; ++reg) {
        int m = blockIdx.x * 128 + wm + i * 16 + quad * 4 + reg;
        int n = bn * 128 + wn + j * 16 + r;
        size_t off = (size_t)m * 1024 + n;
        float z = acc[i][j][reg];
        if (which == 0) {
          Qb[off] = f2bf(z / (1.f + __expf(-z)));      // silu
        } else if (which == 1) {
          float ek = __expf(-z);
          Kb[off] = f2bf(ek / (1.f + ek));              // k = 1 - sigmoid(z)
        } else {
          Vb[off] = f2bf(z);
        }
      }
}

// ---------------------------------------------------------------------------
// Fused scan. grid 4096: blk -> vh = blk&1 (v half), c = (blk>>1)&63 (chunk,
// C=32), bh = blk>>7.  LDS 59008 B -> 2 blocks/CU.
// ---------------------------------------------------------------------------
__global__ __launch_bounds__(256) void hgru_scan(
    const u16* __restrict__ Qg, const u16* __restrict__ Kg, const u16* __restrict__ Vg,
    u16* __restrict__ O) {
  __shared__ alignas(16) char smem[59008];
  float* sb = (float*)(smem);              // [32][129] cumsum (pad: lanes-vary-s reads)
  u16* sU   = (u16*)(smem + 16512);        // [64][136] U^T[vloc][i]
  u16* sKt  = (u16*)(smem + 33920);        // [128][40] khat^T (phase1)
  u16* sVt1 = (u16*)(smem + 44160);        // [64][40]  V^T c-1 (phase1)
  u16* sQ   = (u16*)(smem + 33920);        // [32][136] Qh (phase2)
  u16* sK   = (u16*)(smem + 42624);        // [32][136] Kt (phase2)
  u16* sAm  = (u16*)(smem + 51328);        // [32][40]  masked A
  u16* sVt2 = (u16*)(smem + 53888);        // [64][40]  V^T c

  const int tid = threadIdx.x, blk = blockIdx.x;
  const int vh = blk & 1, c = (blk >> 1) & 63, bh = blk >> 7, h = bh & 7, bb_ = bh >> 3;
  const size_t rb = (size_t)(bb_ * 2048 + c * 32) * 1024 + h * 128;
  const bool haveP = (c > 0);
  const size_t rb1 = haveP ? rb - 32 * 1024 : rb;

  const int lane = tid & 63, wave = tid >> 6;
  const int r = lane & 15, quad = lane >> 4;
  const int ts = tid & 31;                 // row within chunk
  const int g8 = tid >> 5;                 // 0..7

  // prefetch all transform inputs (hide global latency behind cumsum/U-GEMM)
  uint4 Q2[2], K2[2], K1[2], V2, V1;
#pragma unroll
  for (int it = 0; it < 2; ++it) {
    Q2[it] = *(const uint4*)(Qg + rb  + (size_t)ts * 1024 + (it * 8 + g8) * 8);
    K2[it] = *(const uint4*)(Kg + rb  + (size_t)ts * 1024 + (it * 8 + g8) * 8);
    K1[it] = *(const uint4*)(Kg + rb1 + (size_t)ts * 1024 + (it * 8 + g8) * 8);
  }
  V2 = *(const uint4*)(Vg + rb  + (size_t)ts * 1024 + vh * 64 + g8 * 8);
  V1 = *(const uint4*)(Vg + rb1 + (size_t)ts * 1024 + vh * 64 + g8 * 8);

  f32x4 accU[2][4] = {};
  const int vm = (wave & 1) * 32, in = (wave >> 1) * 64;

  if (haveP) {
    // cumsum chunk c-1: g = logsigmoid(1-k), recomputed from bf16 k
    { const int col = tid & 127, half = tid >> 7;
      float run = 0.f;
      const size_t gb = rb1 + (size_t)(half * 16) * 1024 + col;
#pragma unroll
      for (int t = 0; t < 16; ++t) {
        float kv = bf2f(Kg[gb + (size_t)t * 1024]);
        run -= __logf(1.f + __expf(-(1.f - kv)));
        sb[(half * 16 + t) * 129 + col] = run;
      } }
    __syncthreads();
    { if (tid >> 7) { const int col = tid & 127; float fix = sb[15 * 129 + col];
#pragma unroll
        for (int t = 16; t < 32; ++t) sb[t * 129 + col] += fix; } }
    __syncthreads();
    // transform c-1: khat^T[i][s] = k*exp(bC - b_s); V^T (local half)
#pragma unroll
    for (int it = 0; it < 2; ++it) {
      const int i8 = it * 8 + g8;
      const u16* kp = (const u16*)&K1[it];
#pragma unroll
      for (int e = 0; e < 8; ++e) {
        int i = i8 * 8 + e;
        float bs = sb[ts * 129 + i];
        float bC = sb[31 * 129 + i];
        sKt[i * 40 + ts] = f2bf(bf2f(kp[e]) * __expf(bC - bs));
      }
    }
    { const u16* vp = (const u16*)&V1;
#pragma unroll
      for (int e = 0; e < 8; ++e) sVt1[(g8 * 8 + e) * 40 + ts] = vp[e]; }
    __syncthreads();
    // U-GEMM: U^T[vl][i] = sum_s V^T[vl][s] * khat^T[i][s]  (K=32: 1 MFMA/tile)
#pragma unroll
    for (int mi = 0; mi < 2; ++mi) {
      bf16x8 af = *(const bf16x8*)(sVt1 + (vm + mi * 16 + r) * 40 + quad * 8);
#pragma unroll
      for (int nj = 0; nj < 4; ++nj) {
        bf16x8 bv = *(const bf16x8*)(sKt + (in + nj * 16 + r) * 40 + quad * 8);
        accU[mi][nj] = __builtin_amdgcn_mfma_f32_16x16x32_bf16(af, bv, accU[mi][nj], 0, 0, 0);
      }
    }
  }
  // cumsum chunk c (sb overwrite safe: transform1 readers all passed a barrier;
  // U-GEMM touches only sKt/sVt1)
  { const int col = tid & 127, half = tid >> 7;
    float run = 0.f;
    const size_t gb = rb + (size_t)(half * 16) * 1024 + col;
#pragma unroll
    for (int t = 0; t < 16; ++t) {
      float kv = bf2f(Kg[gb + (size_t)t * 1024]);
      run -= __logf(1.f + __expf(-(1.f - kv)));
      sb[(half * 16 + t) * 129 + col] = run;
    } }
  __syncthreads();   // also guarantees every wave finished U-GEMM (sKt/sVt1 free)
  { if (tid >> 7) { const int col = tid & 127; float fix = sb[15 * 129 + col];
#pragma unroll
      for (int t = 16; t < 32; ++t) sb[t * 129 + col] += fix; } }
  if (haveP) {       // spill U accumulator -> sU (disjoint region; read after 2 barriers)
#pragma unroll
    for (int mi = 0; mi < 2; ++mi)
#pragma unroll
      for (int nj = 0; nj < 4; ++nj)
#pragma unroll
        for (int reg = 0; reg < 4; ++reg) {
          int vl = vm + mi * 16 + quad * 4 + reg;
          int i  = in + nj * 16 + r;
          sU[vl * 136 + i] = f2bf(accU[mi][nj][reg]);
        }
  }
  __syncthreads();
  // transform c: Qh = q*exp(b), Kt = k*exp(-b); V^T (local half)
#pragma unroll
  for (int it = 0; it < 2; ++it) {
    const int i8 = it * 8 + g8;
    const u16* qp = (const u16*)&Q2[it];
    const u16* kp = (const u16*)&K2[it];
    u16 qo[8], ko[8];
#pragma unroll
    for (int e = 0; e < 8; ++e) {
      int i = i8 * 8 + e;
      float bt = sb[ts * 129 + i];
      qo[e] = f2bf(bf2f(qp[e]) * __expf(bt));
      ko[e] = f2bf(bf2f(kp[e]) * __expf(-bt));
    }
    *(uint4*)(sQ + ts * 136 + i8 * 8) = *(const uint4*)qo;
    *(uint4*)(sK + ts * 136 + i8 * 8) = *(const uint4*)ko;
  }
  { const u16* vp = (const u16*)&V2;
#pragma unroll
    for (int e = 0; e < 8; ++e) sVt2[(g8 * 8 + e) * 40 + ts] = vp[e]; }
  __syncthreads();
  // GEMM1: Am = tril(Qh Kt^T), 32x32, K=128
  { const int mi = wave & 1, nj = wave >> 1;
    f32x4 a1 = {0.f, 0.f, 0.f, 0.f};
#pragma unroll
    for (int ks = 0; ks < 4; ++ks) {
      bf16x8 af = *(const bf16x8*)(sQ + (mi * 16 + r) * 136 + ks * 32 + quad * 8);
      bf16x8 bk = *(const bf16x8*)(sK + (nj * 16 + r) * 136 + ks * 32 + quad * 8);
      a1 = __builtin_amdgcn_mfma_f32_16x16x32_bf16(af, bk, a1, 0, 0, 0);
    }
#pragma unroll
    for (int reg = 0; reg < 4; ++reg) {
      int t = mi * 16 + quad * 4 + reg, s = nj * 16 + r;
      sAm[t * 40 + s] = (s <= t) ? f2bf(a1[reg]) : (u16)0;
    } }
  __syncthreads();
  // GEMM2: O[t][v] = Am V + Qh U_{c-1}
  { const int mi = wave & 1, no = (wave >> 1) * 32;
    bf16x8 af0 = *(const bf16x8*)(sAm + (mi * 16 + r) * 40 + quad * 8);
    bf16x8 afq[4];
    if (haveP) {
#pragma unroll
      for (int ks = 0; ks < 4; ++ks)
        afq[ks] = *(const bf16x8*)(sQ + (mi * 16 + r) * 136 + ks * 32 + quad * 8);
    }
#pragma unroll
    for (int j = 0; j < 2; ++j) {
      f32x4 acc2 = {0.f, 0.f, 0.f, 0.f};
      bf16x8 bv0 = *(const bf16x8*)(sVt2 + (no + j * 16 + r) * 40 + quad * 8);
      acc2 = __builtin_amdgcn_mfma_f32_16x16x32_bf16(af0, bv0, acc2, 0, 0, 0);
      if (haveP) {
#pragma unroll
        for (int ks = 0; ks < 4; ++ks) {
          bf16x8 bs = *(const bf16x8*)(sU + (no + j * 16 + r) * 136 + ks * 32 + quad * 8);
          acc2 = __builtin_amdgcn_mfma_f32_16x16x32_bf16(afq[ks], bs, acc2, 0, 0, 0);
        }
      }
#pragma unroll
      for (int reg = 0; reg < 4; ++reg) {
        int t = mi * 16 + quad * 4 + reg;
        int vg = vh * 64 + no + j * 16 + r;
        O[rb + (size_t)t * 1024 + vg] = f2bf(acc2[reg]);
      }
    } }
}

__global__ __launch_bounds__(256) void hgru_rmsnorm(const u16* __restrict__ O,
                                                    const float* __restrict__ w,
                                                    u16* __restrict__ On) {
  __shared__ float sred[4];
  const int row = blockIdx.x, tid = threadIdx.x;
  const size_t base = (size_t)row * 1024;
  float vals[4];
  float ss = 0.f;
#pragma unroll
  for (int k = 0; k < 4; ++k) {
    float v = bf2f(O[base + k * 256 + tid]);
    vals[k] = v;
    ss += v * v;
  }
#pragma unroll
  for (int m = 32; m >= 1; m >>= 1) ss += __shfl_xor(ss, m);
  if ((tid & 63) == 0) sred[tid >> 6] = ss;
  __syncthreads();
  float tot = sred[0] + sred[1] + sred[2] + sred[3];
  float scale = rsqrtf(tot * (1.f / 1024.f) + 1e-6f);
#pragma unroll
  for (int k = 0; k < 4; ++k)
    On[base + k * 256 + tid] = f2bf(vals[k] * scale * w[k * 256 + tid]);
}

__global__ __launch_bounds__(256) void hgru_gemm_out(const u16* __restrict__ Ab,
                                                     const u16* __restrict__ Wob,
                                                     float* __restrict__ out) {
  __shared__ alignas(16) u16 smem[16384];
  const u16* Ag = Ab + (size_t)blockIdx.x * 128 * 1024;
  const u16* Bg = Wob + (size_t)blockIdx.y * 128 * 1024;
  f32x4 acc[4][4] = {};
  gemm128_core(Ag, Bg, smem, acc);
  const int tid = threadIdx.x, lane = tid & 63, wave = tid >> 6;
  const int wm = (wave & 1) * 64, wn = (wave >> 1) * 64;
  const int r = lane & 15, quad = lane >> 4;
#pragma unroll
  for (int i = 0; i < 4; ++i)
#pragma unroll
    for (int j = 0; j < 4; ++j)
#pragma unroll
      for (int reg = 0; reg < 4; ++reg) {
        int m = blockIdx.x * 128 + wm + i * 16 + quad * 4 + reg;
        int n = blockIdx.y * 128 + wn + j * 16 + r;
        out[(size_t)m * 1024 + n] = acc[i][j][reg];
      }
}

// ---------------------------------------------------------------------------
extern "C" void kernel_launch(void* const* d_in, const int* in_sizes, int n_in,
                              void* d_out, int out_size, void* d_ws, size_t ws_size,
                              hipStream_t stream) {
  const float* x  = (const float*)d_in[0];
  const float* Wq = (const float*)d_in[1];
  const float* Wk = (const float*)d_in[2];
  const float* Wv = (const float*)d_in[3];
  const float* Wo = (const float*)d_in[4];
  const float* nw = (const float*)d_in[5];
  float* out = (float*)d_out;
  char* ws = (char*)d_ws;

  u16* Xb   = (u16*)(ws + 0);            // 16 MB (reused as normed output later)
  u16* Wqb  = (u16*)(ws + 16777216);
  u16* Wkb  = (u16*)(ws + 18874368);
  u16* Wvb  = (u16*)(ws + 20971520);
  u16* Wob  = (u16*)(ws + 23068672);
  u16* Qb   = (u16*)(ws + 25165824);
  u16* Kb   = (u16*)(ws + 41943040);
  u16* Vb   = (u16*)(ws + 58720256);
  u16* Obf  = (u16*)(ws + 75497472);     // 16 MB scan output
  u16* On   = Xb;

  cast_f32_bf16<<<8192, 256, 0, stream>>>(x, Xb, 2097152);
  dim3 gw(1024, 4);
  cast_w4<<<gw, 256, 0, stream>>>(Wq, Wk, Wv, Wo, Wqb, Wkb, Wvb, Wob);

  dim3 gq(64, 24);
  hgru_gemm_qkv<<<gq, 256, 0, stream>>>(Xb, Wqb, Wkb, Wvb, Qb, Kb, Vb);
  hgru_scan<<<4096, 256, 0, stream>>>(Qb, Kb, Vb, Obf);
  hgru_rmsnorm<<<8192, 256, 0, stream>>>(Obf, nw, On);
  dim3 go(64, 8);
  hgru_gemm_out<<<go, 256, 0, stream>>>(On, Wob, out);
}

// Round 7
// 255.779 us; speedup vs baseline: 1.0285x; 1.0285x over previous
//
#include <hip/hip_runtime.h>
#include <cstdint>
#include <cstddef>

// ---------------------------------------------------------------------------
// Hgru2 (GLA-style gated linear attention), B=4, N=2048, d=1024, h=8, hd=128
//   cast x,W -> bf16
//   gemm_qkv: Q=silu(xWq^T), K=1-sigmoid(xWk^T) (bf16), V (bf16)
//   hgru_scan (C=32, fused): recompute U_{c-1} from chunk c-1 in LDS (1-term
//       state, per-chunk decay <= e^-10), then O = tril(Qh Kt^T) V + Qh U.
//   rmsnorm -> bf16;  gemm_out: out = normed @ Wo^T (f32)
// R7: GEMM core -> BK=32 double-buffer inside 32KB (two 16KB buffers,
//     ONE barrier/kt). Loads for kt+1 issue right after the barrier and age a
//     full compute phase before the next barrier's vmcnt(0) drain -> the
//     ~300-600cyc exposed drain of the R4 2-barrier loop disappears, while
//     occupancy stays at R4's 5 blocks/CU (R2/R3's 64KB dbuf lost it).
// ---------------------------------------------------------------------------

typedef unsigned short u16;
using f32x4  = __attribute__((ext_vector_type(4))) float;
using bf16x8 = __attribute__((ext_vector_type(8))) short;

__device__ __forceinline__ float bf2f(u16 u) {
  union { unsigned int i; float f; } v; v.i = ((unsigned int)u) << 16; return v.f;
}
__device__ __forceinline__ u16 f2bf(float f) {
  union { float f; unsigned int i; } v; v.f = f;
  unsigned int r = v.i + 0x7fffu + ((v.i >> 16) & 1u);
  return (u16)(r >> 16);
}
__device__ __forceinline__ void async_load16(const void* g, void* l) {
  __builtin_amdgcn_global_load_lds(
      (const __attribute__((address_space(1))) unsigned int*)(uintptr_t)g,
      (__attribute__((address_space(3))) unsigned int*)(uintptr_t)l, 16, 0, 0);
}

// ---------------------------------------------------------------------------
// 128x128-tile bf16 GEMM core, C = A * B^T, ld=1024, K=1024. BK=32,
// double-buffered in 32KB total: A0[0,8K) B0[8K,16K) A1[16K,24K) B1[24K,32K).
// 1 barrier/kt; 16 MFMA + 8 ds_read_b128 per wave per kt; 32 kt steps.
// Column-group XOR swizzle (4 groups of 8): conflict-free, loop-invariant.
// ---------------------------------------------------------------------------
__device__ __forceinline__ void gemm128_core(const u16* __restrict__ Ag, const u16* __restrict__ Bg,
                                             u16* smem, f32x4 (&acc)[4][4]) {
  const int tid = threadIdx.x;
  const int lane = tid & 63, wave = tid >> 6;
  const int wm = (wave & 1) * 64, wn = (wave >> 1) * 64;
  const int r = lane & 15, quad = lane >> 4;
  const int xk = r & 3;
  // fragment read bases (elements); buffer swap = +8192 elem (16KB imm)
  const u16* baseA = smem + (wm + r) * 32 + ((quad ^ xk) & 3) * 8;
  const u16* baseB = smem + 4096 + (wn + r) * 32 + ((quad ^ xk) & 3) * 8;
  // staging: row = tid>>2 (64 rows per it), col8 = (tid&3) ^ (row&3)
  const int soff = (tid >> 2) * 1024 + (((tid & 3) ^ ((tid >> 2) & 3)) * 8);
  u16* dA = smem + wave * 512;           // + it*2048 + buf*8192
  u16* dB = smem + 4096 + wave * 512;
  // prologue: stage kt=0 into buf0
#pragma unroll
  for (int it = 0; it < 2; ++it) {
    async_load16(Ag + it * 65536 + soff, dA + it * 2048);
    async_load16(Bg + it * 65536 + soff, dB + it * 2048);
  }
#pragma unroll 2
  for (int kt = 0; kt < 32; ++kt) {
    const int cb = (kt & 1) * 8192;
    __syncthreads();   // drains cur-buffer loads (aged one full compute phase)
    if (kt < 31) {
      const int nb = ((kt + 1) & 1) * 8192;
      const u16* As = Ag + (kt + 1) * 32 + soff;
      const u16* Bs = Bg + (kt + 1) * 32 + soff;
#pragma unroll
      for (int it = 0; it < 2; ++it) {
        async_load16(As + it * 65536, dA + nb + it * 2048);
        async_load16(Bs + it * 65536, dB + nb + it * 2048);
      }
    }
    bf16x8 af[4], bv[4];
#pragma unroll
    for (int i = 0; i < 4; ++i) af[i] = *(const bf16x8*)(baseA + cb + i * 512);
#pragma unroll
    for (int j = 0; j < 4; ++j) bv[j] = *(const bf16x8*)(baseB + cb + j * 512);
#pragma unroll
    for (int i = 0; i < 4; ++i)
#pragma unroll
      for (int j = 0; j < 4; ++j)
        acc[i][j] = __builtin_amdgcn_mfma_f32_16x16x32_bf16(af[i], bv[j], acc[i][j], 0, 0, 0);
  }
}

// ---------------------------------------------------------------------------
__global__ __launch_bounds__(256) void cast_f32_bf16(const float* __restrict__ src,
                                                     u16* __restrict__ dst, int n4) {
  int i = blockIdx.x * 256 + threadIdx.x;
  if (i >= n4) return;
  float4 v = ((const float4*)src)[i];
  unsigned int lo = (unsigned)f2bf(v.x) | ((unsigned)f2bf(v.y) << 16);
  unsigned int hi = (unsigned)f2bf(v.z) | ((unsigned)f2bf(v.w) << 16);
  ((uint2*)dst)[i] = make_uint2(lo, hi);
}

__global__ __launch_bounds__(256) void cast_w4(const float* __restrict__ w0, const float* __restrict__ w1,
                                               const float* __restrict__ w2, const float* __restrict__ w3,
                                               u16* __restrict__ d0, u16* __restrict__ d1,
                                               u16* __restrict__ d2, u16* __restrict__ d3) {
  const float* src = blockIdx.y == 0 ? w0 : (blockIdx.y == 1 ? w1 : (blockIdx.y == 2 ? w2 : w3));
  u16* dst = blockIdx.y == 0 ? d0 : (blockIdx.y == 1 ? d1 : (blockIdx.y == 2 ? d2 : d3));
  int i = blockIdx.x * 256 + threadIdx.x;
  float4 v = ((const float4*)src)[i];
  unsigned int lo = (unsigned)f2bf(v.x) | ((unsigned)f2bf(v.y) << 16);
  unsigned int hi = (unsigned)f2bf(v.z) | ((unsigned)f2bf(v.w) << 16);
  ((uint2*)dst)[i] = make_uint2(lo, hi);
}

// grid (64, 24): y/8 selects {Q,K,V}, y&7 = 128-col block
__global__ __launch_bounds__(256) void hgru_gemm_qkv(
    const u16* __restrict__ Xb, const u16* __restrict__ Wqb, const u16* __restrict__ Wkb,
    const u16* __restrict__ Wvb, u16* __restrict__ Qb, u16* __restrict__ Kb,
    u16* __restrict__ Vb) {
  __shared__ alignas(16) u16 smem[16384];
  const int which = blockIdx.y >> 3, bn = blockIdx.y & 7;
  const u16* W = which == 0 ? Wqb : (which == 1 ? Wkb : Wvb);
  const u16* Ag = Xb + (size_t)blockIdx.x * 128 * 1024;
  const u16* Bg = W + (size_t)bn * 128 * 1024;
  f32x4 acc[4][4] = {};
  gemm128_core(Ag, Bg, smem, acc);
  const int tid = threadIdx.x, lane = tid & 63, wave = tid >> 6;
  const int wm = (wave & 1) * 64, wn = (wave >> 1) * 64;
  const int r = lane & 15, quad = lane >> 4;
#pragma unroll
  for (int i = 0; i < 4; ++i)
#pragma unroll
    for (int j = 0; j < 4; ++j)
#pragma unroll
      for (int reg = 0; reg < 4; ++reg) {
        int m = blockIdx.x * 128 + wm + i * 16 + quad * 4 + reg;
        int n = bn * 128 + wn + j * 16 + r;
        size_t off = (size_t)m * 1024 + n;
        float z = acc[i][j][reg];
        if (which == 0) {
          Qb[off] = f2bf(z / (1.f + __expf(-z)));      // silu
        } else if (which == 1) {
          float ek = __expf(-z);
          Kb[off] = f2bf(ek / (1.f + ek));              // k = 1 - sigmoid(z)
        } else {
          Vb[off] = f2bf(z);
        }
      }
}

// ---------------------------------------------------------------------------
// Fused scan. grid 4096: blk -> vh = blk&1 (v half), c = (blk>>1)&63 (chunk,
// C=32), bh = blk>>7.  LDS 59008 B -> 2 blocks/CU.
// ---------------------------------------------------------------------------
__global__ __launch_bounds__(256) void hgru_scan(
    const u16* __restrict__ Qg, const u16* __restrict__ Kg, const u16* __restrict__ Vg,
    u16* __restrict__ O) {
  __shared__ alignas(16) char smem[59008];
  float* sb = (float*)(smem);              // [32][129] cumsum (pad: lanes-vary-s reads)
  u16* sU   = (u16*)(smem + 16512);        // [64][136] U^T[vloc][i]
  u16* sKt  = (u16*)(smem + 33920);        // [128][40] khat^T (phase1)
  u16* sVt1 = (u16*)(smem + 44160);        // [64][40]  V^T c-1 (phase1)
  u16* sQ   = (u16*)(smem + 33920);        // [32][136] Qh (phase2)
  u16* sK   = (u16*)(smem + 42624);        // [32][136] Kt (phase2)
  u16* sAm  = (u16*)(smem + 51328);        // [32][40]  masked A
  u16* sVt2 = (u16*)(smem + 53888);        // [64][40]  V^T c

  const int tid = threadIdx.x, blk = blockIdx.x;
  const int vh = blk & 1, c = (blk >> 1) & 63, bh = blk >> 7, h = bh & 7, bb_ = bh >> 3;
  const size_t rb = (size_t)(bb_ * 2048 + c * 32) * 1024 + h * 128;
  const bool haveP = (c > 0);
  const size_t rb1 = haveP ? rb - 32 * 1024 : rb;

  const int lane = tid & 63, wave = tid >> 6;
  const int r = lane & 15, quad = lane >> 4;
  const int ts = tid & 31;                 // row within chunk
  const int g8 = tid >> 5;                 // 0..7

  // prefetch all transform inputs (hide global latency behind cumsum/U-GEMM)
  uint4 Q2[2], K2[2], K1[2], V2, V1;
#pragma unroll
  for (int it = 0; it < 2; ++it) {
    Q2[it] = *(const uint4*)(Qg + rb  + (size_t)ts * 1024 + (it * 8 + g8) * 8);
    K2[it] = *(const uint4*)(Kg + rb  + (size_t)ts * 1024 + (it * 8 + g8) * 8);
    K1[it] = *(const uint4*)(Kg + rb1 + (size_t)ts * 1024 + (it * 8 + g8) * 8);
  }
  V2 = *(const uint4*)(Vg + rb  + (size_t)ts * 1024 + vh * 64 + g8 * 8);
  V1 = *(const uint4*)(Vg + rb1 + (size_t)ts * 1024 + vh * 64 + g8 * 8);

  f32x4 accU[2][4] = {};
  const int vm = (wave & 1) * 32, in = (wave >> 1) * 64;

  if (haveP) {
    // cumsum chunk c-1: g = logsigmoid(1-k), recomputed from bf16 k
    { const int col = tid & 127, half = tid >> 7;
      float run = 0.f;
      const size_t gb = rb1 + (size_t)(half * 16) * 1024 + col;
#pragma unroll
      for (int t = 0; t < 16; ++t) {
        float kv = bf2f(Kg[gb + (size_t)t * 1024]);
        run -= __logf(1.f + __expf(-(1.f - kv)));
        sb[(half * 16 + t) * 129 + col] = run;
      } }
    __syncthreads();
    { if (tid >> 7) { const int col = tid & 127; float fix = sb[15 * 129 + col];
#pragma unroll
        for (int t = 16; t < 32; ++t) sb[t * 129 + col] += fix; } }
    __syncthreads();
    // transform c-1: khat^T[i][s] = k*exp(bC - b_s); V^T (local half)
#pragma unroll
    for (int it = 0; it < 2; ++it) {
      const int i8 = it * 8 + g8;
      const u16* kp = (const u16*)&K1[it];
#pragma unroll
      for (int e = 0; e < 8; ++e) {
        int i = i8 * 8 + e;
        float bs = sb[ts * 129 + i];
        float bC = sb[31 * 129 + i];
        sKt[i * 40 + ts] = f2bf(bf2f(kp[e]) * __expf(bC - bs));
      }
    }
    { const u16* vp = (const u16*)&V1;
#pragma unroll
      for (int e = 0; e < 8; ++e) sVt1[(g8 * 8 + e) * 40 + ts] = vp[e]; }
    __syncthreads();
    // U-GEMM: U^T[vl][i] = sum_s V^T[vl][s] * khat^T[i][s]
#pragma unroll
    for (int mi = 0; mi < 2; ++mi) {
      bf16x8 af = *(const bf16x8*)(sVt1 + (vm + mi * 16 + r) * 40 + quad * 8);
#pragma unroll
      for (int nj = 0; nj < 4; ++nj) {
        bf16x8 bv = *(const bf16x8*)(sKt + (in + nj * 16 + r) * 40 + quad * 8);
        accU[mi][nj] = __builtin_amdgcn_mfma_f32_16x16x32_bf16(af, bv, accU[mi][nj], 0, 0, 0);
      }
    }
  }
  // cumsum chunk c
  { const int col = tid & 127, half = tid >> 7;
    float run = 0.f;
    const size_t gb = rb + (size_t)(half * 16) * 1024 + col;
#pragma unroll
    for (int t = 0; t < 16; ++t) {
      float kv = bf2f(Kg[gb + (size_t)t * 1024]);
      run -= __logf(1.f + __expf(-(1.f - kv)));
      sb[(half * 16 + t) * 129 + col] = run;
    } }
  __syncthreads();   // also guarantees every wave finished U-GEMM (sKt/sVt1 free)
  { if (tid >> 7) { const int col = tid & 127; float fix = sb[15 * 129 + col];
#pragma unroll
      for (int t = 16; t < 32; ++t) sb[t * 129 + col] += fix; } }
  if (haveP) {       // spill U accumulator -> sU
#pragma unroll
    for (int mi = 0; mi < 2; ++mi)
#pragma unroll
      for (int nj = 0; nj < 4; ++nj)
#pragma unroll
        for (int reg = 0; reg < 4; ++reg) {
          int vl = vm + mi * 16 + quad * 4 + reg;
          int i  = in + nj * 16 + r;
          sU[vl * 136 + i] = f2bf(accU[mi][nj][reg]);
        }
  }
  __syncthreads();
  // transform c: Qh = q*exp(b), Kt = k*exp(-b); V^T (local half)
#pragma unroll
  for (int it = 0; it < 2; ++it) {
    const int i8 = it * 8 + g8;
    const u16* qp = (const u16*)&Q2[it];
    const u16* kp = (const u16*)&K2[it];
    u16 qo[8], ko[8];
#pragma unroll
    for (int e = 0; e < 8; ++e) {
      int i = i8 * 8 + e;
      float bt = sb[ts * 129 + i];
      qo[e] = f2bf(bf2f(qp[e]) * __expf(bt));
      ko[e] = f2bf(bf2f(kp[e]) * __expf(-bt));
    }
    *(uint4*)(sQ + ts * 136 + i8 * 8) = *(const uint4*)qo;
    *(uint4*)(sK + ts * 136 + i8 * 8) = *(const uint4*)ko;
  }
  { const u16* vp = (const u16*)&V2;
#pragma unroll
    for (int e = 0; e < 8; ++e) sVt2[(g8 * 8 + e) * 40 + ts] = vp[e]; }
  __syncthreads();
  // GEMM1: Am = tril(Qh Kt^T), 32x32, K=128
  { const int mi = wave & 1, nj = wave >> 1;
    f32x4 a1 = {0.f, 0.f, 0.f, 0.f};
#pragma unroll
    for (int ks = 0; ks < 4; ++ks) {
      bf16x8 af = *(const bf16x8*)(sQ + (mi * 16 + r) * 136 + ks * 32 + quad * 8);
      bf16x8 bk = *(const bf16x8*)(sK + (nj * 16 + r) * 136 + ks * 32 + quad * 8);
      a1 = __builtin_amdgcn_mfma_f32_16x16x32_bf16(af, bk, a1, 0, 0, 0);
    }
#pragma unroll
    for (int reg = 0; reg < 4; ++reg) {
      int t = mi * 16 + quad * 4 + reg, s = nj * 16 + r;
      sAm[t * 40 + s] = (s <= t) ? f2bf(a1[reg]) : (u16)0;
    } }
  __syncthreads();
  // GEMM2: O[t][v] = Am V + Qh U_{c-1}
  { const int mi = wave & 1, no = (wave >> 1) * 32;
    bf16x8 af0 = *(const bf16x8*)(sAm + (mi * 16 + r) * 40 + quad * 8);
    bf16x8 afq[4];
    if (haveP) {
#pragma unroll
      for (int ks = 0; ks < 4; ++ks)
        afq[ks] = *(const bf16x8*)(sQ + (mi * 16 + r) * 136 + ks * 32 + quad * 8);
    }
#pragma unroll
    for (int j = 0; j < 2; ++j) {
      f32x4 acc2 = {0.f, 0.f, 0.f, 0.f};
      bf16x8 bv0 = *(const bf16x8*)(sVt2 + (no + j * 16 + r) * 40 + quad * 8);
      acc2 = __builtin_amdgcn_mfma_f32_16x16x32_bf16(af0, bv0, acc2, 0, 0, 0);
      if (haveP) {
#pragma unroll
        for (int ks = 0; ks < 4; ++ks) {
          bf16x8 bs = *(const bf16x8*)(sU + (no + j * 16 + r) * 136 + ks * 32 + quad * 8);
          acc2 = __builtin_amdgcn_mfma_f32_16x16x32_bf16(afq[ks], bs, acc2, 0, 0, 0);
        }
      }
#pragma unroll
      for (int reg = 0; reg < 4; ++reg) {
        int t = mi * 16 + quad * 4 + reg;
        int vg = vh * 64 + no + j * 16 + r;
        O[rb + (size_t)t * 1024 + vg] = f2bf(acc2[reg]);
      }
    } }
}

__global__ __launch_bounds__(256) void hgru_rmsnorm(const u16* __restrict__ O,
                                                    const float* __restrict__ w,
                                                    u16* __restrict__ On) {
  __shared__ float sred[4];
  const int row = blockIdx.x, tid = threadIdx.x;
  const size_t base = (size_t)row * 1024;
  float vals[4];
  float ss = 0.f;
#pragma unroll
  for (int k = 0; k < 4; ++k) {
    float v = bf2f(O[base + k * 256 + tid]);
    vals[k] = v;
    ss += v * v;
  }
#pragma unroll
  for (int m = 32; m >= 1; m >>= 1) ss += __shfl_xor(ss, m);
  if ((tid & 63) == 0) sred[tid >> 6] = ss;
  __syncthreads();
  float tot = sred[0] + sred[1] + sred[2] + sred[3];
  float scale = rsqrtf(tot * (1.f / 1024.f) + 1e-6f);
#pragma unroll
  for (int k = 0; k < 4; ++k)
    On[base + k * 256 + tid] = f2bf(vals[k] * scale * w[k * 256 + tid]);
}

__global__ __launch_bounds__(256) void hgru_gemm_out(const u16* __restrict__ Ab,
                                                     const u16* __restrict__ Wob,
                                                     float* __restrict__ out) {
  __shared__ alignas(16) u16 smem[16384];
  const u16* Ag = Ab + (size_t)blockIdx.x * 128 * 1024;
  const u16* Bg = Wob + (size_t)blockIdx.y * 128 * 1024;
  f32x4 acc[4][4] = {};
  gemm128_core(Ag, Bg, smem, acc);
  const int tid = threadIdx.x, lane = tid & 63, wave = tid >> 6;
  const int wm = (wave & 1) * 64, wn = (wave >> 1) * 64;
  const int r = lane & 15, quad = lane >> 4;
#pragma unroll
  for (int i = 0; i < 4; ++i)
#pragma unroll
    for (int j = 0; j < 4; ++j)
#pragma unroll
      for (int reg = 0; reg < 4; ++reg) {
        int m = blockIdx.x * 128 + wm + i * 16 + quad * 4 + reg;
        int n = blockIdx.y * 128 + wn + j * 16 + r;
        out[(size_t)m * 1024 + n] = acc[i][j][reg];
      }
}

// ---------------------------------------------------------------------------
extern "C" void kernel_launch(void* const* d_in, const int* in_sizes, int n_in,
                              void* d_out, int out_size, void* d_ws, size_t ws_size,
                              hipStream_t stream) {
  const float* x  = (const float*)d_in[0];
  const float* Wq = (const float*)d_in[1];
  const float* Wk = (const float*)d_in[2];
  const float* Wv = (const float*)d_in[3];
  const float* Wo = (const float*)d_in[4];
  const float* nw = (const float*)d_in[5];
  float* out = (float*)d_out;
  char* ws = (char*)d_ws;

  u16* Xb   = (u16*)(ws + 0);            // 16 MB (reused as normed output later)
  u16* Wqb  = (u16*)(ws + 16777216);
  u16* Wkb  = (u16*)(ws + 18874368);
  u16* Wvb  = (u16*)(ws + 20971520);
  u16* Wob  = (u16*)(ws + 23068672);
  u16* Qb   = (u16*)(ws + 25165824);
  u16* Kb   = (u16*)(ws + 41943040);
  u16* Vb   = (u16*)(ws + 58720256);
  u16* Obf  = (u16*)(ws + 75497472);     // 16 MB scan output
  u16* On   = Xb;

  cast_f32_bf16<<<8192, 256, 0, stream>>>(x, Xb, 2097152);
  dim3 gw(1024, 4);
  cast_w4<<<gw, 256, 0, stream>>>(Wq, Wk, Wv, Wo, Wqb, Wkb, Wvb, Wob);

  dim3 gq(64, 24);
  hgru_gemm_qkv<<<gq, 256, 0, stream>>>(Xb, Wqb, Wkb, Wvb, Qb, Kb, Vb);
  hgru_scan<<<4096, 256, 0, stream>>>(Qb, Kb, Vb, Obf);
  hgru_rmsnorm<<<8192, 256, 0, stream>>>(Obf, nw, On);
  dim3 go(64, 8);
  hgru_gemm_out<<<go, 256, 0, stream>>>(On, Wob, out);
}

// Round 8
// 239.473 us; speedup vs baseline: 1.0985x; 1.0681x over previous
//
#include <hip/hip_runtime.h>
#include <cstdint>
#include <cstddef>

// ---------------------------------------------------------------------------
// Hgru2 (GLA-style gated linear attention), B=4, N=2048, d=1024, h=8, hd=128
//   cast x -> bf16; cast W -> bf16 (Wo gets norm_w folded into its columns)
//   gemm_qkv: Q=silu(xWq^T), K=1-sigmoid(xWk^T) (bf16), V (bf16)
//   hgru_scan (C=32, fused): recompute U_{c-1} from chunk c-1 in LDS (1-term
//       state, per-chunk decay <= e^-10), then O = tril(Qh Kt^T) V + Qh U.
//   sumsq: s[m] = rsqrt(mean(O[m]^2)+eps)
//   gemm_out: out[m][n] = s[m] * (O @ (Wo . w)^T)[m][n]   (rmsnorm folded)
// R8: scan LDS 59008 -> 42496 B (3 blocks/CU, was 2) via register-held U
//     accumulator + buffer overlays; rmsnorm kernel deleted (w folded into
//     Wo cast, per-row scale in gemm_out epilogue).
// ---------------------------------------------------------------------------

typedef unsigned short u16;
using f32x4  = __attribute__((ext_vector_type(4))) float;
using bf16x8 = __attribute__((ext_vector_type(8))) short;

__device__ __forceinline__ float bf2f(u16 u) {
  union { unsigned int i; float f; } v; v.i = ((unsigned int)u) << 16; return v.f;
}
__device__ __forceinline__ u16 f2bf(float f) {
  union { float f; unsigned int i; } v; v.f = f;
  unsigned int r = v.i + 0x7fffu + ((v.i >> 16) & 1u);
  return (u16)(r >> 16);
}
__device__ __forceinline__ void async_load16(const void* g, void* l) {
  __builtin_amdgcn_global_load_lds(
      (const __attribute__((address_space(1))) unsigned int*)(uintptr_t)g,
      (__attribute__((address_space(3))) unsigned int*)(uintptr_t)l, 16, 0, 0);
}

// ---------------------------------------------------------------------------
// 128x128-tile bf16 GEMM core (R7): BK=32, double-buffered in 32KB,
// 1 barrier/kt, loads age a full compute phase before the drain.
// ---------------------------------------------------------------------------
__device__ __forceinline__ void gemm128_core(const u16* __restrict__ Ag, const u16* __restrict__ Bg,
                                             u16* smem, f32x4 (&acc)[4][4]) {
  const int tid = threadIdx.x;
  const int lane = tid & 63, wave = tid >> 6;
  const int wm = (wave & 1) * 64, wn = (wave >> 1) * 64;
  const int r = lane & 15, quad = lane >> 4;
  const int xk = r & 3;
  const u16* baseA = smem + (wm + r) * 32 + ((quad ^ xk) & 3) * 8;
  const u16* baseB = smem + 4096 + (wn + r) * 32 + ((quad ^ xk) & 3) * 8;
  const int soff = (tid >> 2) * 1024 + (((tid & 3) ^ ((tid >> 2) & 3)) * 8);
  u16* dA = smem + wave * 512;           // + it*2048 + buf*8192
  u16* dB = smem + 4096 + wave * 512;
#pragma unroll
  for (int it = 0; it < 2; ++it) {
    async_load16(Ag + it * 65536 + soff, dA + it * 2048);
    async_load16(Bg + it * 65536 + soff, dB + it * 2048);
  }
#pragma unroll 2
  for (int kt = 0; kt < 32; ++kt) {
    const int cb = (kt & 1) * 8192;
    __syncthreads();
    if (kt < 31) {
      const int nb = ((kt + 1) & 1) * 8192;
      const u16* As = Ag + (kt + 1) * 32 + soff;
      const u16* Bs = Bg + (kt + 1) * 32 + soff;
#pragma unroll
      for (int it = 0; it < 2; ++it) {
        async_load16(As + it * 65536, dA + nb + it * 2048);
        async_load16(Bs + it * 65536, dB + nb + it * 2048);
      }
    }
    bf16x8 af[4], bv[4];
#pragma unroll
    for (int i = 0; i < 4; ++i) af[i] = *(const bf16x8*)(baseA + cb + i * 512);
#pragma unroll
    for (int j = 0; j < 4; ++j) bv[j] = *(const bf16x8*)(baseB + cb + j * 512);
#pragma unroll
    for (int i = 0; i < 4; ++i)
#pragma unroll
      for (int j = 0; j < 4; ++j)
        acc[i][j] = __builtin_amdgcn_mfma_f32_16x16x32_bf16(af[i], bv[j], acc[i][j], 0, 0, 0);
  }
}

// ---------------------------------------------------------------------------
__global__ __launch_bounds__(256) void cast_f32_bf16(const float* __restrict__ src,
                                                     u16* __restrict__ dst, int n4) {
  int i = blockIdx.x * 256 + threadIdx.x;
  if (i >= n4) return;
  float4 v = ((const float4*)src)[i];
  unsigned int lo = (unsigned)f2bf(v.x) | ((unsigned)f2bf(v.y) << 16);
  unsigned int hi = (unsigned)f2bf(v.z) | ((unsigned)f2bf(v.w) << 16);
  ((uint2*)dst)[i] = make_uint2(lo, hi);
}

// 4 weight casts; Wo (y==3) gets norm_w folded into its columns.
__global__ __launch_bounds__(256) void cast_w4(const float* __restrict__ w0, const float* __restrict__ w1,
                                               const float* __restrict__ w2, const float* __restrict__ w3,
                                               const float* __restrict__ nw,
                                               u16* __restrict__ d0, u16* __restrict__ d1,
                                               u16* __restrict__ d2, u16* __restrict__ d3) {
  const float* src = blockIdx.y == 0 ? w0 : (blockIdx.y == 1 ? w1 : (blockIdx.y == 2 ? w2 : w3));
  u16* dst = blockIdx.y == 0 ? d0 : (blockIdx.y == 1 ? d1 : (blockIdx.y == 2 ? d2 : d3));
  int i = blockIdx.x * 256 + threadIdx.x;
  float4 v = ((const float4*)src)[i];
  if (blockIdx.y == 3) {
    float4 wv = ((const float4*)nw)[i & 255];   // k = (i*4..i*4+3) % 1024
    v.x *= wv.x; v.y *= wv.y; v.z *= wv.z; v.w *= wv.w;
  }
  unsigned int lo = (unsigned)f2bf(v.x) | ((unsigned)f2bf(v.y) << 16);
  unsigned int hi = (unsigned)f2bf(v.z) | ((unsigned)f2bf(v.w) << 16);
  ((uint2*)dst)[i] = make_uint2(lo, hi);
}

// grid (64, 24): y/8 selects {Q,K,V}, y&7 = 128-col block
__global__ __launch_bounds__(256) void hgru_gemm_qkv(
    const u16* __restrict__ Xb, const u16* __restrict__ Wqb, const u16* __restrict__ Wkb,
    const u16* __restrict__ Wvb, u16* __restrict__ Qb, u16* __restrict__ Kb,
    u16* __restrict__ Vb) {
  __shared__ alignas(16) u16 smem[16384];
  const int which = blockIdx.y >> 3, bn = blockIdx.y & 7;
  const u16* W = which == 0 ? Wqb : (which == 1 ? Wkb : Wvb);
  const u16* Ag = Xb + (size_t)blockIdx.x * 128 * 1024;
  const u16* Bg = W + (size_t)bn * 128 * 1024;
  f32x4 acc[4][4] = {};
  gemm128_core(Ag, Bg, smem, acc);
  const int tid = threadIdx.x, lane = tid & 63, wave = tid >> 6;
  const int wm = (wave & 1) * 64, wn = (wave >> 1) * 64;
  const int r = lane & 15, quad = lane >> 4;
#pragma unroll
  for (int i = 0; i < 4; ++i)
#pragma unroll
    for (int j = 0; j < 4; ++j)
#pragma unroll
      for (int reg = 0; reg < 4; ++reg) {
        int m = blockIdx.x * 128 + wm + i * 16 + quad * 4 + reg;
        int n = bn * 128 + wn + j * 16 + r;
        size_t off = (size_t)m * 1024 + n;
        float z = acc[i][j][reg];
        if (which == 0) {
          Qb[off] = f2bf(z / (1.f + __expf(-z)));      // silu
        } else if (which == 1) {
          float ek = __expf(-z);
          Kb[off] = f2bf(ek / (1.f + ek));              // k = 1 - sigmoid(z)
        } else {
          Vb[off] = f2bf(z);
        }
      }
}

// ---------------------------------------------------------------------------
// Fused scan. grid 4096: blk -> vh = blk&1 (v half), c = (blk>>1)&63 (chunk,
// C=32), bh = blk>>7.  LDS 42496 B -> 3 blocks/CU (R7: 59008 -> 2/CU).
// U accumulator held in registers through cumsum2/transform-c; sU overlays
// the dead sb region, sQ/sK overlay the dead phase-1 transposes.
// ---------------------------------------------------------------------------
__global__ __launch_bounds__(256) void hgru_scan(
    const u16* __restrict__ Qg, const u16* __restrict__ Kg, const u16* __restrict__ Vg,
    u16* __restrict__ O) {
  __shared__ alignas(16) char smem[42496];
  float* sb  = (float*)(smem);             // [32][129] cumsum    [0,16512)
  u16* sU    = (u16*)(smem);               // [64][136] U^T       [0,17408)  after transform-c
  u16* sKt   = (u16*)(smem + 17408);       // [128][40] phase1    [17408,27648)
  u16* sVt1  = (u16*)(smem + 27648);       // [64][40]  phase1    [27648,32768)
  u16* sQ    = (u16*)(smem + 17408);       // [32][136] phase2    [17408,26112)
  u16* sK    = (u16*)(smem + 26112);       // [32][136] phase2    [26112,34816)
  u16* sVt2  = (u16*)(smem + 34816);       // [64][40]            [34816,39936)
  u16* sAm   = (u16*)(smem + 39936);       // [32][40]            [39936,42496)

  const int tid = threadIdx.x, blk = blockIdx.x;
  const int vh = blk & 1, c = (blk >> 1) & 63, bh = blk >> 7, h = bh & 7, bb_ = bh >> 3;
  const size_t rb = (size_t)(bb_ * 2048 + c * 32) * 1024 + h * 128;
  const bool haveP = (c > 0);
  const size_t rb1 = haveP ? rb - 32 * 1024 : rb;

  const int lane = tid & 63, wave = tid >> 6;
  const int r = lane & 15, quad = lane >> 4;
  const int ts = tid & 31;                 // row within chunk
  const int g8 = tid >> 5;                 // 0..7

  // prefetch all transform inputs
  uint4 Q2[2], K2[2], K1[2], V2, V1;
#pragma unroll
  for (int it = 0; it < 2; ++it) {
    Q2[it] = *(const uint4*)(Qg + rb  + (size_t)ts * 1024 + (it * 8 + g8) * 8);
    K2[it] = *(const uint4*)(Kg + rb  + (size_t)ts * 1024 + (it * 8 + g8) * 8);
    K1[it] = *(const uint4*)(Kg + rb1 + (size_t)ts * 1024 + (it * 8 + g8) * 8);
  }
  V2 = *(const uint4*)(Vg + rb  + (size_t)ts * 1024 + vh * 64 + g8 * 8);
  V1 = *(const uint4*)(Vg + rb1 + (size_t)ts * 1024 + vh * 64 + g8 * 8);

  f32x4 accU[2][4] = {};
  const int vm = (wave & 1) * 32, in = (wave >> 1) * 64;

  if (haveP) {
    // cumsum chunk c-1
    { const int col = tid & 127, half = tid >> 7;
      float run = 0.f;
      const size_t gb = rb1 + (size_t)(half * 16) * 1024 + col;
#pragma unroll
      for (int t = 0; t < 16; ++t) {
        float kv = bf2f(Kg[gb + (size_t)t * 1024]);
        run -= __logf(1.f + __expf(-(1.f - kv)));
        sb[(half * 16 + t) * 129 + col] = run;
      } }
    __syncthreads();
    { if (tid >> 7) { const int col = tid & 127; float fix = sb[15 * 129 + col];
#pragma unroll
        for (int t = 16; t < 32; ++t) sb[t * 129 + col] += fix; } }
    __syncthreads();
    // transform c-1: khat^T[i][s] = k*exp(bC - b_s); V^T (local half)
#pragma unroll
    for (int it = 0; it < 2; ++it) {
      const int i8 = it * 8 + g8;
      const u16* kp = (const u16*)&K1[it];
#pragma unroll
      for (int e = 0; e < 8; ++e) {
        int i = i8 * 8 + e;
        float bs = sb[ts * 129 + i];
        float bC = sb[31 * 129 + i];
        sKt[i * 40 + ts] = f2bf(bf2f(kp[e]) * __expf(bC - bs));
      }
    }
    { const u16* vp = (const u16*)&V1;
#pragma unroll
      for (int e = 0; e < 8; ++e) sVt1[(g8 * 8 + e) * 40 + ts] = vp[e]; }
    __syncthreads();
    // U-GEMM into registers (reads sKt/sVt1)
#pragma unroll
    for (int mi = 0; mi < 2; ++mi) {
      bf16x8 af = *(const bf16x8*)(sVt1 + (vm + mi * 16 + r) * 40 + quad * 8);
#pragma unroll
      for (int nj = 0; nj < 4; ++nj) {
        bf16x8 bv = *(const bf16x8*)(sKt + (in + nj * 16 + r) * 40 + quad * 8);
        accU[mi][nj] = __builtin_amdgcn_mfma_f32_16x16x32_bf16(af, bv, accU[mi][nj], 0, 0, 0);
      }
    }
  }
  // cumsum chunk c (sb writes OK: transform c-1 readers passed the pre-U-GEMM
  // barrier; U-GEMM touches only sKt/sVt1)
  { const int col = tid & 127, half = tid >> 7;
    float run = 0.f;
    const size_t gb = rb + (size_t)(half * 16) * 1024 + col;
#pragma unroll
    for (int t = 0; t < 16; ++t) {
      float kv = bf2f(Kg[gb + (size_t)t * 1024]);
      run -= __logf(1.f + __expf(-(1.f - kv)));
      sb[(half * 16 + t) * 129 + col] = run;
    } }
  __syncthreads();
  { if (tid >> 7) { const int col = tid & 127; float fix = sb[15 * 129 + col];
#pragma unroll
      for (int t = 16; t < 32; ++t) sb[t * 129 + col] += fix; } }
  __syncthreads();
  // transform c: Qh = q*exp(b), Kt = k*exp(-b) -> sQ/sK (overlay dead sKt/sVt1)
#pragma unroll
  for (int it = 0; it < 2; ++it) {
    const int i8 = it * 8 + g8;
    const u16* qp = (const u16*)&Q2[it];
    const u16* kp = (const u16*)&K2[it];
    u16 qo[8], ko[8];
#pragma unroll
    for (int e = 0; e < 8; ++e) {
      int i = i8 * 8 + e;
      float bt = sb[ts * 129 + i];
      qo[e] = f2bf(bf2f(qp[e]) * __expf(bt));
      ko[e] = f2bf(bf2f(kp[e]) * __expf(-bt));
    }
    *(uint4*)(sQ + ts * 136 + i8 * 8) = *(const uint4*)qo;
    *(uint4*)(sK + ts * 136 + i8 * 8) = *(const uint4*)ko;
  }
  { const u16* vp = (const u16*)&V2;
#pragma unroll
    for (int e = 0; e < 8; ++e) sVt2[(g8 * 8 + e) * 40 + ts] = vp[e]; }
  __syncthreads();
  // GEMM1: Am = tril(Qh Kt^T) (32x32, K=128); then spill accU -> sU
  // (sU overlays sb, dead: all waves passed the post-transform-c barrier)
  { const int mi = wave & 1, nj = wave >> 1;
    f32x4 a1 = {0.f, 0.f, 0.f, 0.f};
#pragma unroll
    for (int ks = 0; ks < 4; ++ks) {
      bf16x8 af = *(const bf16x8*)(sQ + (mi * 16 + r) * 136 + ks * 32 + quad * 8);
      bf16x8 bk = *(const bf16x8*)(sK + (nj * 16 + r) * 136 + ks * 32 + quad * 8);
      a1 = __builtin_amdgcn_mfma_f32_16x16x32_bf16(af, bk, a1, 0, 0, 0);
    }
#pragma unroll
    for (int reg = 0; reg < 4; ++reg) {
      int t = mi * 16 + quad * 4 + reg, s = nj * 16 + r;
      sAm[t * 40 + s] = (s <= t) ? f2bf(a1[reg]) : (u16)0;
    } }
  if (haveP) {
#pragma unroll
    for (int mi = 0; mi < 2; ++mi)
#pragma unroll
      for (int nj = 0; nj < 4; ++nj)
#pragma unroll
        for (int reg = 0; reg < 4; ++reg) {
          int vl = vm + mi * 16 + quad * 4 + reg;
          int i  = in + nj * 16 + r;
          sU[vl * 136 + i] = f2bf(accU[mi][nj][reg]);
        }
  }
  __syncthreads();
  // GEMM2: O[t][v] = Am V + Qh U_{c-1}
  { const int mi = wave & 1, no = (wave >> 1) * 32;
    bf16x8 af0 = *(const bf16x8*)(sAm + (mi * 16 + r) * 40 + quad * 8);
    bf16x8 afq[4];
    if (haveP) {
#pragma unroll
      for (int ks = 0; ks < 4; ++ks)
        afq[ks] = *(const bf16x8*)(sQ + (mi * 16 + r) * 136 + ks * 32 + quad * 8);
    }
#pragma unroll
    for (int j = 0; j < 2; ++j) {
      f32x4 acc2 = {0.f, 0.f, 0.f, 0.f};
      bf16x8 bv0 = *(const bf16x8*)(sVt2 + (no + j * 16 + r) * 40 + quad * 8);
      acc2 = __builtin_amdgcn_mfma_f32_16x16x32_bf16(af0, bv0, acc2, 0, 0, 0);
      if (haveP) {
#pragma unroll
        for (int ks = 0; ks < 4; ++ks) {
          bf16x8 bs = *(const bf16x8*)(sU + (no + j * 16 + r) * 136 + ks * 32 + quad * 8);
          acc2 = __builtin_amdgcn_mfma_f32_16x16x32_bf16(afq[ks], bs, acc2, 0, 0, 0);
        }
      }
#pragma unroll
      for (int reg = 0; reg < 4; ++reg) {
        int t = mi * 16 + quad * 4 + reg;
        int vg = vh * 64 + no + j * 16 + r;
        O[rb + (size_t)t * 1024 + vg] = f2bf(acc2[reg]);
      }
    } }
}

// s[m] = rsqrt(mean(O[m]^2)+eps); grid 2048, one wave per row
__global__ __launch_bounds__(256) void hgru_sumsq(const u16* __restrict__ O,
                                                  float* __restrict__ s) {
  const int row = blockIdx.x * 4 + (threadIdx.x >> 6);
  const int lane = threadIdx.x & 63;
  const u16* p = O + (size_t)row * 1024 + lane * 16;
  uint4 a = *(const uint4*)p;
  uint4 b = *(const uint4*)(p + 8);
  float ss = 0.f;
  const unsigned int* w = (const unsigned int*)&a;
#pragma unroll
  for (int e = 0; e < 4; ++e) {
    float lo = bf2f((u16)(w[e] & 0xffff)), hi = bf2f((u16)(w[e] >> 16));
    ss += lo * lo + hi * hi;
  }
  const unsigned int* w2 = (const unsigned int*)&b;
#pragma unroll
  for (int e = 0; e < 4; ++e) {
    float lo = bf2f((u16)(w2[e] & 0xffff)), hi = bf2f((u16)(w2[e] >> 16));
    ss += lo * lo + hi * hi;
  }
#pragma unroll
  for (int m = 32; m >= 1; m >>= 1) ss += __shfl_xor(ss, m);
  if (lane == 0) s[row] = rsqrtf(ss * (1.f / 1024.f) + 1e-6f);
}

// out[m][n] = s[m] * (O @ Wo'^T)[m][n], Wo' = Wo . norm_w (folded at cast)
__global__ __launch_bounds__(256) void hgru_gemm_out(const u16* __restrict__ Ab,
                                                     const u16* __restrict__ Wob,
                                                     const float* __restrict__ s,
                                                     float* __restrict__ out) {
  __shared__ alignas(16) u16 smem[16384];
  const u16* Ag = Ab + (size_t)blockIdx.x * 128 * 1024;
  const u16* Bg = Wob + (size_t)blockIdx.y * 128 * 1024;
  f32x4 acc[4][4] = {};
  gemm128_core(Ag, Bg, smem, acc);
  const int tid = threadIdx.x, lane = tid & 63, wave = tid >> 6;
  const int wm = (wave & 1) * 64, wn = (wave >> 1) * 64;
  const int r = lane & 15, quad = lane >> 4;
#pragma unroll
  for (int i = 0; i < 4; ++i)
#pragma unroll
    for (int reg = 0; reg < 4; ++reg) {
      int m = blockIdx.x * 128 + wm + i * 16 + quad * 4 + reg;
      float sm = s[m];
#pragma unroll
      for (int j = 0; j < 4; ++j) {
        int n = blockIdx.y * 128 + wn + j * 16 + r;
        out[(size_t)m * 1024 + n] = acc[i][j][reg] * sm;
      }
    }
}

// ---------------------------------------------------------------------------
extern "C" void kernel_launch(void* const* d_in, const int* in_sizes, int n_in,
                              void* d_out, int out_size, void* d_ws, size_t ws_size,
                              hipStream_t stream) {
  const float* x  = (const float*)d_in[0];
  const float* Wq = (const float*)d_in[1];
  const float* Wk = (const float*)d_in[2];
  const float* Wv = (const float*)d_in[3];
  const float* Wo = (const float*)d_in[4];
  const float* nw = (const float*)d_in[5];
  float* out = (float*)d_out;
  char* ws = (char*)d_ws;

  u16* Xb   = (u16*)(ws + 0);            // 16 MB
  u16* Wqb  = (u16*)(ws + 16777216);
  u16* Wkb  = (u16*)(ws + 18874368);
  u16* Wvb  = (u16*)(ws + 20971520);
  u16* Wob  = (u16*)(ws + 23068672);
  u16* Qb   = (u16*)(ws + 25165824);     // 16 MB
  u16* Kb   = (u16*)(ws + 41943040);     // 16 MB
  u16* Vb   = (u16*)(ws + 58720256);     // 16 MB
  u16* Obf  = (u16*)(ws + 75497472);     // 16 MB scan output
  float* Sv = (float*)(ws + 92274688);   // 32 KB row scales

  cast_f32_bf16<<<8192, 256, 0, stream>>>(x, Xb, 2097152);
  dim3 gw(1024, 4);
  cast_w4<<<gw, 256, 0, stream>>>(Wq, Wk, Wv, Wo, nw, Wqb, Wkb, Wvb, Wob);

  dim3 gq(64, 24);
  hgru_gemm_qkv<<<gq, 256, 0, stream>>>(Xb, Wqb, Wkb, Wvb, Qb, Kb, Vb);
  hgru_scan<<<4096, 256, 0, stream>>>(Qb, Kb, Vb, Obf);
  hgru_sumsq<<<2048, 256, 0, stream>>>(Obf, Sv);
  dim3 go(64, 8);
  hgru_gemm_out<<<go, 256, 0, stream>>>(Obf, Wob, Sv, out);
}